// Round 1
// baseline (4333.553 us; speedup 1.0000x reference)
//
#include <hip/hip_runtime.h>

#define N_NODES 50000
#define N_EDGES 800000
#define HEADS 4
#define NUM_GRAPHS 8

// ---------------- Kernel A: h0 = relu(x@W0+b0); xw1 = h0@W1 ----------------
__global__ __launch_bounds__(256) void fc0_xw1_kernel(
    const float* __restrict__ x,
    const float* __restrict__ fc0_w, const float* __restrict__ fc0_b,
    const float* __restrict__ w1,
    float* __restrict__ h0, float* __restrict__ xw1) {
  __shared__ float sW0[3 * 16];
  __shared__ float sB0[16];
  __shared__ float sW1[16 * 128];
  for (int i = threadIdx.x; i < 48; i += blockDim.x) sW0[i] = fc0_w[i];
  for (int i = threadIdx.x; i < 16; i += blockDim.x) sB0[i] = fc0_b[i];
  for (int i = threadIdx.x; i < 16 * 128; i += blockDim.x) sW1[i] = w1[i];
  __syncthreads();
  int n = blockIdx.x * blockDim.x + threadIdx.x;
  if (n >= N_NODES) return;
  float x0 = x[n * 3 + 0], x1 = x[n * 3 + 1], x2 = x[n * 3 + 2];
  float h[16];
#pragma unroll
  for (int j = 0; j < 16; j++) {
    float v = x0 * sW0[0 * 16 + j] + x1 * sW0[1 * 16 + j] + x2 * sW0[2 * 16 + j] + sB0[j];
    h[j] = fmaxf(v, 0.f);
    h0[(size_t)n * 16 + j] = h[j];
  }
  for (int k = 0; k < 128; k++) {
    float s = 0.f;
#pragma unroll
    for (int j = 0; j < 16; j++) s += h[j] * sW1[j * 128 + k];
    xw1[(size_t)n * 128 + k] = s;
  }
}

// ---------------- Edge pass (templated on channel sizes) ----------------
template <int CIN, int COUT>
__global__ __launch_bounds__(256) void edge_kernel(
    const int* __restrict__ src, const int* __restrict__ dst,
    const float* __restrict__ h, const float* __restrict__ xw,
    const float* __restrict__ u, const float* __restrict__ cb,
    float* __restrict__ agg, float* __restrict__ cnt) {
  int e = blockIdx.x * blockDim.x + threadIdx.x;
  if (e >= N_EDGES) return;
  int s = src[e];
  int d = dst[e];
  // t = h[s] - h[d]
  float t[CIN];
  const float4* hs4 = reinterpret_cast<const float4*>(h + (size_t)s * CIN);
  const float4* hd4 = reinterpret_cast<const float4*>(h + (size_t)d * CIN);
#pragma unroll
  for (int j = 0; j < CIN / 4; j++) {
    float4 a = hs4[j];
    float4 b = hd4[j];
    t[4 * j + 0] = a.x - b.x;
    t[4 * j + 1] = a.y - b.y;
    t[4 * j + 2] = a.z - b.z;
    t[4 * j + 3] = a.w - b.w;
  }
  float logit[HEADS];
#pragma unroll
  for (int hh = 0; hh < HEADS; hh++) {
    float acc = cb[hh];
#pragma unroll
    for (int j = 0; j < CIN; j++) acc += t[j] * u[j * HEADS + hh];
    logit[hh] = acc;
  }
  float m = fmaxf(fmaxf(logit[0], logit[1]), fmaxf(logit[2], logit[3]));
  float q[HEADS];
  float ssum = 0.f;
#pragma unroll
  for (int hh = 0; hh < HEADS; hh++) {
    q[hh] = __expf(logit[hh] - m);
    ssum += q[hh];
  }
  float inv = 1.f / ssum;
#pragma unroll
  for (int hh = 0; hh < HEADS; hh++) q[hh] *= inv;

  const float* xws = xw + (size_t)s * HEADS * COUT;
  float* aggd = agg + (size_t)d * COUT;
#pragma unroll
  for (int c = 0; c < COUT; c += 4) {
    float4 a0 = *reinterpret_cast<const float4*>(xws + 0 * COUT + c);
    float4 a1 = *reinterpret_cast<const float4*>(xws + 1 * COUT + c);
    float4 a2 = *reinterpret_cast<const float4*>(xws + 2 * COUT + c);
    float4 a3 = *reinterpret_cast<const float4*>(xws + 3 * COUT + c);
    float mx = q[0] * a0.x + q[1] * a1.x + q[2] * a2.x + q[3] * a3.x;
    float my = q[0] * a0.y + q[1] * a1.y + q[2] * a2.y + q[3] * a3.y;
    float mz = q[0] * a0.z + q[1] * a1.z + q[2] * a2.z + q[3] * a3.z;
    float mw = q[0] * a0.w + q[1] * a1.w + q[2] * a2.w + q[3] * a3.w;
    atomicAdd(&aggd[c + 0], mx);
    atomicAdd(&aggd[c + 1], my);
    atomicAdd(&aggd[c + 2], mz);
    atomicAdd(&aggd[c + 3], mw);
  }
  if (cnt) atomicAdd(&cnt[d], 1.0f);
}

// ---------------- Kernel C: h1 = relu(agg/deg + b1); xw2 = h1@W2 ----------------
__global__ __launch_bounds__(256) void finalize1_kernel(
    const float* __restrict__ agg, const float* __restrict__ cnt,
    const float* __restrict__ b1, const float* __restrict__ w2,
    float* __restrict__ h1, float* __restrict__ xw2) {
  __shared__ float sW2[32 * 256];  // 32 KB
  for (int i = threadIdx.x; i < 32 * 256; i += blockDim.x) sW2[i] = w2[i];
  __syncthreads();
  int n = blockIdx.x * blockDim.x + threadIdx.x;
  if (n >= N_NODES) return;
  float inv = 1.f / fmaxf(cnt[n], 1.f);
  float h[32];
#pragma unroll
  for (int j = 0; j < 32; j++) {
    float v = agg[(size_t)n * 32 + j] * inv + b1[j];
    h[j] = fmaxf(v, 0.f);
    h1[(size_t)n * 32 + j] = h[j];
  }
  for (int k = 0; k < 256; k++) {
    float s = 0.f;
#pragma unroll
    for (int j = 0; j < 32; j++) s += h[j] * sW2[j * 256 + k];
    xw2[(size_t)n * 256 + k] = s;
  }
}

// ---------------- Kernel E: h2 = relu(agg2/deg + b2); pool per graph ----------------
// One thread per channel (64 threads/block); block covers a chunk of nodes.
// batch is sorted, so accumulate in a register and flush on graph change.
#define POOL_CHUNK 512
__global__ __launch_bounds__(64) void finalize2_pool_kernel(
    const float* __restrict__ agg, const float* __restrict__ cnt,
    const float* __restrict__ b2, const int* __restrict__ batch,
    float* __restrict__ gsum, float* __restrict__ gcnt) {
  int c = threadIdx.x;  // 0..63
  int n0 = blockIdx.x * POOL_CHUNK;
  int n1 = min(n0 + POOL_CHUNK, N_NODES);
  if (n0 >= N_NODES) return;
  float bc = b2[c];
  float acc = 0.f;
  float cacc = 0.f;
  int curg = batch[n0];
  for (int n = n0; n < n1; n++) {
    int g = batch[n];
    float inv = 1.f / fmaxf(cnt[n], 1.f);
    float v = fmaxf(agg[(size_t)n * 64 + c] * inv + bc, 0.f);
    if (g != curg) {
      atomicAdd(&gsum[curg * 64 + c], acc);
      if (c == 0) atomicAdd(&gcnt[curg], cacc);
      acc = 0.f;
      cacc = 0.f;
      curg = g;
    }
    acc += v;
    cacc += 1.f;
  }
  atomicAdd(&gsum[curg * 64 + c], acc);
  if (c == 0) atomicAdd(&gcnt[curg], cacc);
}

// ---------------- Kernel F: out = (gsum/gcnt) @ fc1_w + fc1_b ----------------
__global__ __launch_bounds__(128) void head_kernel(
    const float* __restrict__ gsum, const float* __restrict__ gcnt,
    const float* __restrict__ fc1_w, const float* __restrict__ fc1_b,
    float* __restrict__ out) {
  int t = threadIdx.x;
  if (t >= NUM_GRAPHS * 10) return;
  int g = t / 10, k = t % 10;
  float inv = 1.f / fmaxf(gcnt[g], 1.f);
  float s = fc1_b[k];
#pragma unroll
  for (int c = 0; c < 64; c++) s += gsum[g * 64 + c] * inv * fc1_w[c * 10 + k];
  out[g * 10 + k] = s;
}

extern "C" void kernel_launch(void* const* d_in, const int* in_sizes, int n_in,
                              void* d_out, int out_size, void* d_ws, size_t ws_size,
                              hipStream_t stream) {
  const float* x = (const float*)d_in[0];
  const int* edge_index = (const int*)d_in[1];  // [2,E] flat: src then dst
  const int* batch = (const int*)d_in[2];
  const float* fc0_w = (const float*)d_in[3];
  const float* fc0_b = (const float*)d_in[4];
  const float* u1 = (const float*)d_in[5];
  const float* c1 = (const float*)d_in[6];
  const float* w1 = (const float*)d_in[7];
  const float* b1 = (const float*)d_in[8];
  const float* u2 = (const float*)d_in[9];
  const float* c2 = (const float*)d_in[10];
  const float* w2 = (const float*)d_in[11];
  const float* b2 = (const float*)d_in[12];
  const float* fc1_w = (const float*)d_in[13];
  const float* fc1_b = (const float*)d_in[14];
  float* out = (float*)d_out;

  const int* src = edge_index;            // edge_index[0] = x_j source
  const int* dst = edge_index + N_EDGES;  // edge_index[1] = x_i dest

  // Workspace layout (floats). Zero-init region first, then scratch.
  float* ws = (float*)d_ws;
  float* agg1 = ws;                                   // N*32
  float* cnt = agg1 + (size_t)N_NODES * 32;           // N
  float* agg2 = cnt + N_NODES;                        // N*64
  float* gsum = agg2 + (size_t)N_NODES * 64;          // 8*64
  float* gcnt = gsum + NUM_GRAPHS * 64;               // 8
  float* h0 = gcnt + NUM_GRAPHS;                      // N*16
  float* xw1 = h0 + (size_t)N_NODES * 16;             // N*128
  float* h1 = xw1 + (size_t)N_NODES * 128;            // N*32
  float* xw2 = h1 + (size_t)N_NODES * 32;             // N*256

  size_t zero_bytes = ((size_t)N_NODES * (32 + 1 + 64) + NUM_GRAPHS * 64 + NUM_GRAPHS) * sizeof(float);
  hipMemsetAsync(d_ws, 0, zero_bytes, stream);

  int nblk = (N_NODES + 255) / 256;
  int eblk = (N_EDGES + 255) / 256;

  fc0_xw1_kernel<<<nblk, 256, 0, stream>>>(x, fc0_w, fc0_b, w1, h0, xw1);
  edge_kernel<16, 32><<<eblk, 256, 0, stream>>>(src, dst, h0, xw1, u1, c1, agg1, cnt);
  finalize1_kernel<<<nblk, 256, 0, stream>>>(agg1, cnt, b1, w2, h1, xw2);
  edge_kernel<32, 64><<<eblk, 256, 0, stream>>>(src, dst, h1, xw2, u2, c2, agg2, nullptr);
  int pblk = (N_NODES + POOL_CHUNK - 1) / POOL_CHUNK;
  finalize2_pool_kernel<<<pblk, 64, 0, stream>>>(agg2, cnt, b2, batch, gsum, gcnt);
  head_kernel<<<1, 128, 0, stream>>>(gsum, gcnt, fc1_w, fc1_b, out);
}

// Round 2
// 771.356 us; speedup vs baseline: 5.6181x; 5.6181x over previous
//
#include <hip/hip_runtime.h>

#define N_NODES 50000
#define N_EDGES 800000
#define HEADS 4
#define NUM_GRAPHS 8

// ============ CSR build ============
__global__ __launch_bounds__(256) void hist_kernel(const int* __restrict__ dst,
                                                   int* __restrict__ deg) {
  int e = blockIdx.x * blockDim.x + threadIdx.x;
  if (e < N_EDGES) atomicAdd(&deg[dst[e]], 1);
}

#define SCAN_T 1024
__global__ __launch_bounds__(SCAN_T) void scan_kernel(const int* __restrict__ deg,
                                                      int* __restrict__ rowstart,
                                                      int* __restrict__ cursor) {
  __shared__ int part[SCAN_T];
  int t = threadIdx.x;
  const int chunk = (N_NODES + SCAN_T - 1) / SCAN_T;  // 49
  int lo = t * chunk, hi = min(lo + chunk, N_NODES);
  int sum = 0;
  for (int i = lo; i < hi; i++) sum += deg[i];
  part[t] = sum;
  __syncthreads();
  for (int off = 1; off < SCAN_T; off <<= 1) {
    int v = part[t];
    int u = (t >= off) ? part[t - off] : 0;
    __syncthreads();
    part[t] = v + u;
    __syncthreads();
  }
  int base = (t == 0) ? 0 : part[t - 1];
  for (int i = lo; i < hi; i++) {
    rowstart[i] = base;
    cursor[i] = base;
    base += deg[i];
  }
  if (t == SCAN_T - 1) rowstart[N_NODES] = base;
}

__global__ __launch_bounds__(256) void scatter_kernel(const int* __restrict__ dst,
                                                      int* __restrict__ cursor,
                                                      int* __restrict__ eidx) {
  int e = blockIdx.x * blockDim.x + threadIdx.x;
  if (e >= N_EDGES) return;
  int p = atomicAdd(&cursor[dst[e]], 1);
  eidx[p] = e;
}

// ============ Kernel A: h0 = relu(x@W0+b0); xw1 = h0@W1 ============
__global__ __launch_bounds__(256) void fc0_xw1_kernel(
    const float* __restrict__ x,
    const float* __restrict__ fc0_w, const float* __restrict__ fc0_b,
    const float* __restrict__ w1,
    float* __restrict__ h0, float* __restrict__ xw1) {
  __shared__ float sW0[3 * 16];
  __shared__ float sB0[16];
  __shared__ float sW1[16 * 128];
  for (int i = threadIdx.x; i < 48; i += blockDim.x) sW0[i] = fc0_w[i];
  for (int i = threadIdx.x; i < 16; i += blockDim.x) sB0[i] = fc0_b[i];
  for (int i = threadIdx.x; i < 16 * 128; i += blockDim.x) sW1[i] = w1[i];
  __syncthreads();
  int n = blockIdx.x * blockDim.x + threadIdx.x;
  if (n >= N_NODES) return;
  float x0 = x[n * 3 + 0], x1 = x[n * 3 + 1], x2 = x[n * 3 + 2];
  float h[16];
#pragma unroll
  for (int j = 0; j < 16; j++) {
    float v = x0 * sW0[0 * 16 + j] + x1 * sW0[1 * 16 + j] + x2 * sW0[2 * 16 + j] + sB0[j];
    h[j] = fmaxf(v, 0.f);
    h0[(size_t)n * 16 + j] = h[j];
  }
  for (int k = 0; k < 128; k++) {
    float s = 0.f;
#pragma unroll
    for (int j = 0; j < 16; j++) s += h[j] * sW1[j * 128 + k];
    xw1[(size_t)n * 128 + k] = s;
  }
}

// ============ Q kernel: per-edge head softmax (no atomics) ============
template <int CIN>
__global__ __launch_bounds__(256) void q_kernel(
    const int* __restrict__ src, const int* __restrict__ dst,
    const float* __restrict__ h,
    const float* __restrict__ u, const float* __restrict__ cb,
    float* __restrict__ q) {
  int e = blockIdx.x * blockDim.x + threadIdx.x;
  if (e >= N_EDGES) return;
  int s = src[e];
  int d = dst[e];
  float t[CIN];
  const float4* hs4 = reinterpret_cast<const float4*>(h + (size_t)s * CIN);
  const float4* hd4 = reinterpret_cast<const float4*>(h + (size_t)d * CIN);
#pragma unroll
  for (int j = 0; j < CIN / 4; j++) {
    float4 a = hs4[j];
    float4 b = hd4[j];
    t[4 * j + 0] = a.x - b.x;
    t[4 * j + 1] = a.y - b.y;
    t[4 * j + 2] = a.z - b.z;
    t[4 * j + 3] = a.w - b.w;
  }
  float logit[HEADS];
#pragma unroll
  for (int hh = 0; hh < HEADS; hh++) {
    float acc = cb[hh];
#pragma unroll
    for (int j = 0; j < CIN; j++) acc += t[j] * u[j * HEADS + hh];
    logit[hh] = acc;
  }
  float m = fmaxf(fmaxf(logit[0], logit[1]), fmaxf(logit[2], logit[3]));
  float qv[HEADS];
  float ssum = 0.f;
#pragma unroll
  for (int hh = 0; hh < HEADS; hh++) {
    qv[hh] = __expf(logit[hh] - m);
    ssum += qv[hh];
  }
  float inv = 1.f / ssum;
  float4 out = make_float4(qv[0] * inv, qv[1] * inv, qv[2] * inv, qv[3] * inv);
  *reinterpret_cast<float4*>(q + 4 * (size_t)e) = out;
}

// ============ AGG kernel: per-node gather, COUT threads per node ============
template <int COUT>
__global__ __launch_bounds__(256) void agg_kernel(
    const int* __restrict__ rowstart, const int* __restrict__ eidx,
    const int* __restrict__ src, const float* __restrict__ q,
    const float* __restrict__ xw, const float* __restrict__ b,
    float* __restrict__ hout) {
  constexpr int NPB = 256 / COUT;
  int node = blockIdx.x * NPB + threadIdx.x / COUT;
  int c = threadIdx.x % COUT;
  if (node >= N_NODES) return;
  int e0 = rowstart[node], e1 = rowstart[node + 1];
  float acc = 0.f;
  for (int p = e0; p < e1; p++) {
    int e = eidx[p];
    int s = src[e];
    const float4 qv = *reinterpret_cast<const float4*>(q + 4 * (size_t)e);
    const float* row = xw + (size_t)s * HEADS * COUT + c;
    float a0 = row[0];
    float a1 = row[COUT];
    float a2 = row[2 * COUT];
    float a3 = row[3 * COUT];
    acc += qv.x * a0 + qv.y * a1 + qv.z * a2 + qv.w * a3;
  }
  float invn = 1.f / fmaxf((float)(e1 - e0), 1.f);
  hout[(size_t)node * COUT + c] = fmaxf(acc * invn + b[c], 0.f);
}

// ============ GEMM: xw2 = h1 @ W2  ([N,32]@[32,256]) ============
__global__ __launch_bounds__(256) void gemm2_kernel(
    const float* __restrict__ h1, const float* __restrict__ w2,
    float* __restrict__ xw2) {
  __shared__ float sW2[32 * 256];  // 32 KB
  for (int i = threadIdx.x; i < 32 * 256; i += blockDim.x) sW2[i] = w2[i];
  __syncthreads();
  int n = blockIdx.x * blockDim.x + threadIdx.x;
  if (n >= N_NODES) return;
  float h[32];
#pragma unroll
  for (int j = 0; j < 32; j++) h[j] = h1[(size_t)n * 32 + j];
  for (int k = 0; k < 256; k++) {
    float s = 0.f;
#pragma unroll
    for (int j = 0; j < 32; j++) s += h[j] * sW2[j * 256 + k];
    xw2[(size_t)n * 256 + k] = s;
  }
}

// ============ Pool: per-graph mean of h2 (batch sorted) ============
#define POOL_CHUNK 512
__global__ __launch_bounds__(64) void pool_kernel(
    const float* __restrict__ h2, const int* __restrict__ batch,
    float* __restrict__ gsum, float* __restrict__ gcnt) {
  int c = threadIdx.x;  // 0..63
  int n0 = blockIdx.x * POOL_CHUNK;
  int n1 = min(n0 + POOL_CHUNK, N_NODES);
  if (n0 >= N_NODES) return;
  float acc = 0.f;
  float cacc = 0.f;
  int curg = batch[n0];
  for (int n = n0; n < n1; n++) {
    int g = batch[n];
    float v = h2[(size_t)n * 64 + c];
    if (g != curg) {
      atomicAdd(&gsum[curg * 64 + c], acc);
      if (c == 0) atomicAdd(&gcnt[curg], cacc);
      acc = 0.f;
      cacc = 0.f;
      curg = g;
    }
    acc += v;
    cacc += 1.f;
  }
  atomicAdd(&gsum[curg * 64 + c], acc);
  if (c == 0) atomicAdd(&gcnt[curg], cacc);
}

// ============ Head: out = (gsum/gcnt) @ fc1_w + fc1_b ============
__global__ __launch_bounds__(128) void head_kernel(
    const float* __restrict__ gsum, const float* __restrict__ gcnt,
    const float* __restrict__ fc1_w, const float* __restrict__ fc1_b,
    float* __restrict__ out) {
  int t = threadIdx.x;
  if (t >= NUM_GRAPHS * 10) return;
  int g = t / 10, k = t % 10;
  float inv = 1.f / fmaxf(gcnt[g], 1.f);
  float s = fc1_b[k];
#pragma unroll
  for (int c = 0; c < 64; c++) s += gsum[g * 64 + c] * inv * fc1_w[c * 10 + k];
  out[g * 10 + k] = s;
}

extern "C" void kernel_launch(void* const* d_in, const int* in_sizes, int n_in,
                              void* d_out, int out_size, void* d_ws, size_t ws_size,
                              hipStream_t stream) {
  const float* x = (const float*)d_in[0];
  const int* edge_index = (const int*)d_in[1];
  const int* batch = (const int*)d_in[2];
  const float* fc0_w = (const float*)d_in[3];
  const float* fc0_b = (const float*)d_in[4];
  const float* u1 = (const float*)d_in[5];
  const float* c1 = (const float*)d_in[6];
  const float* w1 = (const float*)d_in[7];
  const float* b1 = (const float*)d_in[8];
  const float* u2 = (const float*)d_in[9];
  const float* c2 = (const float*)d_in[10];
  const float* w2 = (const float*)d_in[11];
  const float* b2 = (const float*)d_in[12];
  const float* fc1_w = (const float*)d_in[13];
  const float* fc1_b = (const float*)d_in[14];
  float* out = (float*)d_out;

  const int* src = edge_index;            // x_j
  const int* dst = edge_index + N_EDGES;  // x_i

  // ---- workspace layout (4-byte units; all offsets %4==0 -> 16B aligned) ----
  char* wsb = (char*)d_ws;
  int* deg = (int*)wsb;                         // N
  int* rowstart = deg + N_NODES;                // N+1
  int* cursor = rowstart + N_NODES + 1;         // N
  int* eidx = cursor + N_NODES;                 // E
  // pad to multiple of 4 units: 950001 -> 950004
  float* q = (float*)(wsb) + 950004;            // E*4 = 3.2M
  float* h0 = q + (size_t)N_EDGES * 4;          // N*16
  float* xw1 = h0 + (size_t)N_NODES * 16;       // N*128 (h2 aliases this after AGG1)
  float* h2 = xw1;                              // N*64, alias (xw1 dead after agg1)
  float* h1 = xw1 + (size_t)N_NODES * 128;      // N*32
  float* xw2 = h1 + (size_t)N_NODES * 32;       // N*256
  float* gsum = xw2 + (size_t)N_NODES * 256;    // 8*64
  float* gcnt = gsum + NUM_GRAPHS * 64;         // 8

  hipMemsetAsync(deg, 0, N_NODES * sizeof(int), stream);
  hipMemsetAsync(gsum, 0, (NUM_GRAPHS * 64 + NUM_GRAPHS) * sizeof(float), stream);

  int nblk = (N_NODES + 255) / 256;
  int eblk = (N_EDGES + 255) / 256;

  // CSR build
  hist_kernel<<<eblk, 256, 0, stream>>>(dst, deg);
  scan_kernel<<<1, SCAN_T, 0, stream>>>(deg, rowstart, cursor);
  scatter_kernel<<<eblk, 256, 0, stream>>>(dst, cursor, eidx);

  // Layer 0 + transform for layer 1
  fc0_xw1_kernel<<<nblk, 256, 0, stream>>>(x, fc0_w, fc0_b, w1, h0, xw1);

  // FeaStConv 1
  q_kernel<16><<<eblk, 256, 0, stream>>>(src, dst, h0, u1, c1, q);
  agg_kernel<32><<<(N_NODES + 7) / 8, 256, 0, stream>>>(rowstart, eidx, src, q, xw1, b1, h1);

  // Transform for layer 2
  gemm2_kernel<<<nblk, 256, 0, stream>>>(h1, w2, xw2);

  // FeaStConv 2 (h2 aliases xw1 region — xw1 is dead now)
  q_kernel<32><<<eblk, 256, 0, stream>>>(src, dst, h1, u2, c2, q);
  agg_kernel<64><<<(N_NODES + 3) / 4, 256, 0, stream>>>(rowstart, eidx, src, q, xw2, b2, h2);

  // Pool + head
  int pblk = (N_NODES + POOL_CHUNK - 1) / POOL_CHUNK;
  pool_kernel<<<pblk, 64, 0, stream>>>(h2, batch, gsum, gcnt);
  head_kernel<<<1, 128, 0, stream>>>(gsum, gcnt, fc1_w, fc1_b, out);
}